// Round 13
// baseline (182.216 us; speedup 1.0000x reference)
//
#include <hip/hip_runtime.h>
#include <hip/hip_bf16.h>
#include <stdint.h>

// Problem constants (N,C,H,W = 4,128,64,64)
#define NB 4
#define CH 128
#define LL 4096   // H*W

typedef __attribute__((ext_vector_type(8))) short short8;   // 8 bf16 MFMA A/B frag
typedef __attribute__((ext_vector_type(4))) short short4b;  // 4 bf16 (8B)
typedef __attribute__((ext_vector_type(4))) float floatx4;  // 16x16 C/D frag
typedef __attribute__((ext_vector_type(16))) float floatx16; // 32x32 C/D frag

// Frag-major layout (verified R9-R12): element (row r, k) of 16-wide tile t:
//   t*2048 + (k>>5)*512 + ((k>>3)&3)*128 + (r&15)*8 + (k&7)
// One 16x16x32 frag (tile t, slice s) = 512 contiguous shorts; lane L reads
// [8L, 8L+8) — fully coalesced; identical mapping for A- and B-frags.

static __device__ __forceinline__ short f2bf(float f) {
    uint32_t u = __float_as_uint(f);
    u += 0x7fffu + ((u >> 16) & 1u);
    return (short)(u >> 16);
}
static __device__ __forceinline__ float bf2f(short s) {
    return __uint_as_float(((uint32_t)(uint16_t)s) << 16);
}

// ---------------------------------------------------------------------------
// Kernel 1: QKV projection via MFMA; W converted inline (fp32 reads are
// L1/L2-hot: 192 KB/block, 64 KB/matrix resident after first touch) —
// wprep dispatch eliminated. x read once. Outputs Qf/Kf frag-major
// (K pre-scaled 1/sqrt(C)), Vp panel [n][l>>4][c][l&15].
// grid = 4n*128 lt = 512 blocks x 256 thr.
// ---------------------------------------------------------------------------
__global__ __launch_bounds__(256) void proj_kernel(
    const float* __restrict__ x,
    const float* __restrict__ Wq, const float* __restrict__ bq,
    const float* __restrict__ Wk, const float* __restrict__ bk,
    const float* __restrict__ Wv, const float* __restrict__ bv,
    short* __restrict__ Qf, short* __restrict__ Kf, short* __restrict__ Vp)
{
    const int b    = blockIdx.x;
    const int n    = b >> 7;
    const int lt   = b & 127;         // l-tile of 32
    const int l0   = lt << 5;
    const int tid  = threadIdx.x;
    const int wave = tid >> 6;        // 0..3
    const int lane = tid & 63;
    const int quad = lane >> 4;
    const int mc   = lane & 15;

    __shared__ short Xb[32][136];     // [l][c] bf16, +8 pad (8.7 KB)

    {
        const int sl = tid & 31;      // l
        const int cg = tid >> 5;      // c-group of 16 (0..7)
        const float* xp = x + ((size_t)n * CH + cg * 16) * LL + l0 + sl;
        short8 buf;
        #pragma unroll
        for (int i = 0; i < 16; ++i) {
            buf[i & 7] = f2bf(xp[(size_t)i * LL]);
            if ((i & 7) == 7)
                *(short8*)(void*)&Xb[sl][cg * 16 + (i & 8)] = buf;
        }
    }
    __syncthreads();

    const int lt2 = wave >> 1;        // l-subtile of 16
    const int oh  = wave & 1;         // o-half (4 o-tiles)
    const int gt  = lt * 2 + lt2;     // global 16-l tile index

    short8 xf[4];                     // B-frags: B[k=c][col=l]
    #pragma unroll
    for (int s = 0; s < 4; ++s)
        xf[s] = *(const short8*)(const void*)&Xb[lt2 * 16 + mc][32 * s + quad * 8];

    const size_t obase = ((size_t)n * 256 + gt) * 2048;
    const float scale = 0.08838834764831845f;  // 1/sqrt(128)

    #pragma unroll
    for (int mat = 0; mat < 3; ++mat) {
        const float* Wm = (mat == 0) ? Wq : (mat == 1) ? Wk : Wv;
        const float* bb = (mat == 0) ? bq : (mat == 1) ? bk : bv;
        const float wscale = (mat == 1) ? scale : 1.0f;
        #pragma unroll
        for (int ot = oh * 4; ot < oh * 4 + 4; ++ot) {
            floatx4 acc = {0.f, 0.f, 0.f, 0.f};
            #pragma unroll
            for (int s = 0; s < 4; ++s) {
                // inline W cvt: A[row=o=ot*16+mc][k=c=32s+8q+j]
                const float* wp = Wm + (ot * 16 + mc) * CH + 32 * s + quad * 8;
                const floatx4 w0 = *(const floatx4*)(const void*)(wp);
                const floatx4 w1 = *(const floatx4*)(const void*)(wp + 4);
                short8 wf;
                #pragma unroll
                for (int j = 0; j < 4; ++j) {
                    wf[j]     = f2bf(w0[j] * wscale);
                    wf[4 + j] = f2bf(w1[j] * wscale);
                }
                acc = __builtin_amdgcn_mfma_f32_16x16x32_bf16(wf, xf[s], acc, 0, 0, 0);
            }
            const int c0 = ot * 16 + 4 * quad;
            if (mat < 2) {
                short4b pv;
                #pragma unroll
                for (int r = 0; r < 4; ++r)
                    pv[r] = f2bf(acc[r] + bb[c0 + r] * wscale);
                short* dst = ((mat == 0) ? Qf : Kf) + obase
                           + (c0 >> 5) * 512 + ((c0 >> 3) & 3) * 128
                           + mc * 8 + (c0 & 7);
                *(short4b*)(void*)dst = pv;
            } else {
                #pragma unroll
                for (int r = 0; r < 4; ++r)
                    Vp[obase + (c0 + r) * 16 + mc] = f2bf(acc[r] + bb[c0 + r]);
            }
        }
    }
}

// ---------------------------------------------------------------------------
// Kernel 2: softmax denominators + V scaling, fused. Block owns 32 l
// exclusively: 2 K-tiles resident/wave, 4 waves sweep m-quarters (R12
// structure), LDS combine (NO atomics, NO zeroed global Dsum), then the
// whole block writes Vs[:, l-slice] = Vp * (1/D[l]). attn needs no D.
// grid = 4n * 128 tp = 512 blocks x 256 thr.
// ---------------------------------------------------------------------------
__global__ __launch_bounds__(256) void rowsum_kernel(
    const short* __restrict__ Qf, const short* __restrict__ Kf,
    const short* __restrict__ Vp, short* __restrict__ Vs)
{
    const int b    = blockIdx.x;
    const int n    = b >> 7;
    const int tp   = b & 127;            // K-tile pair (32 l)
    const int tid  = threadIdx.x;
    const int wave = tid >> 6;           // m-quarter
    const int lane = tid & 63;
    const int quad = lane >> 4;
    const int mc   = lane & 15;

    __shared__ float Db[4][32];          // per-wave partial D
    __shared__ float Dr[32];             // rcpD for local 32 l

    const short* Kb = Kf + ((size_t)n * 256 + tp * 2) * 2048 + lane * 8;
    short8 kf[2][4];
    #pragma unroll
    for (int t = 0; t < 2; ++t)
        #pragma unroll
        for (int s = 0; s < 4; ++s)
            kf[t][s] = *(const short8*)(const void*)(Kb + t * 2048 + s * 512);

    const short* Qn = Qf + (size_t)n * 524288 + (size_t)wave * 64 * 2048 + lane * 8;
    float rs[2][4] = {{0.f,0.f,0.f,0.f},{0.f,0.f,0.f,0.f}};

    for (int i = 0; i < 64; i += 2) {        // 4 independent MFMA chains
        floatx4 a[2][2];
        #pragma unroll
        for (int t = 0; t < 2; ++t)
            #pragma unroll
            for (int j = 0; j < 2; ++j) a[t][j] = (floatx4){0.f,0.f,0.f,0.f};
        #pragma unroll
        for (int s = 0; s < 4; ++s) {
            const short8 q0 = *(const short8*)(const void*)(Qn + (size_t)i * 2048 + s * 512);
            const short8 q1 = *(const short8*)(const void*)(Qn + (size_t)(i + 1) * 2048 + s * 512);
            #pragma unroll
            for (int t = 0; t < 2; ++t) {
                a[t][0] = __builtin_amdgcn_mfma_f32_16x16x32_bf16(kf[t][s], q0, a[t][0], 0, 0, 0);
                a[t][1] = __builtin_amdgcn_mfma_f32_16x16x32_bf16(kf[t][s], q1, a[t][1], 0, 0, 0);
            }
        }
        #pragma unroll
        for (int t = 0; t < 2; ++t)
            #pragma unroll
            for (int j = 0; j < 2; ++j)
                #pragma unroll
                for (int r = 0; r < 4; ++r) rs[t][r] += __expf(a[t][j][r]);
    }

    #pragma unroll
    for (int t = 0; t < 2; ++t) {
        #pragma unroll
        for (int r = 0; r < 4; ++r) {        // reduce over m (col lanes)
            float v = rs[t][r];
            v += __shfl_xor(v, 1);
            v += __shfl_xor(v, 2);
            v += __shfl_xor(v, 4);
            v += __shfl_xor(v, 8);
            rs[t][r] = v;
        }
        if (mc == 0) {
            #pragma unroll
            for (int r = 0; r < 4; ++r)      // local l = t*16 + quad*4 + r
                Db[wave][t * 16 + quad * 4 + r] = rs[t][r];
        }
    }
    __syncthreads();
    if (tid < 32)
        Dr[tid] = 1.0f / (Db[0][tid] + Db[1][tid] + Db[2][tid] + Db[3][tid]);
    __syncthreads();

    // ---- fused V scaling: Vs[:, l-slice] = Vp * rcpD[l] ----
    const short* vsrc = Vp + ((size_t)n * 256 + tp * 2) * 2048;
    short*       vdst = Vs + ((size_t)n * 256 + tp * 2) * 2048;
    #pragma unroll
    for (int k = 0; k < 16; ++k) {
        const int i = k * 256 + tid;         // 0..4095, coalesced
        const int tile = i >> 11;            // 0/1
        const int li   = i & 15;
        vdst[i] = f2bf(bf2f(vsrc[i]) * Dr[tile * 16 + li]);
    }
}

// ---------------------------------------------------------------------------
// Kernel 3: O[c,m] = sum_l V'[c,l]*exp(S[l,m]);  out = x + O  (V' pre-scaled
// by 1/D). R12 structure (m-block 64, 1024 thr, P dbuf, 1 barrier/step) with
// Q frags REGISTER-RESIDENT (removes 4 MB/block Q re-reads) and D loads gone.
// grid = 4n * 64 m-blocks = 256 blocks x 1024 thr.
// ---------------------------------------------------------------------------
__global__ __launch_bounds__(1024) void attn_out_kernel(
    const short* __restrict__ Qf, const short* __restrict__ Kf,
    const short* __restrict__ Vs,
    const float* __restrict__ x, float* __restrict__ out)
{
    const int b    = blockIdx.x;
    const int n    = b >> 6;
    const int m0   = (b & 63) << 6;     // m-block of 64
    const int tid  = threadIdx.x;
    const int wave = tid >> 6;          // 0..15
    const int lane = tid & 63;
    const int quad = lane >> 4;
    const int mc   = lane & 15;
    const int l32  = lane & 31;
    const int h    = lane >> 5;
    const int ct   = wave & 3;          // c-tile (32 channels)
    const int mh   = (wave >> 2) & 1;   // m-half (32 cols)
    const int kh   = wave >> 3;         // kc-half

    __shared__ short P[2][64][264];     // dbuf [m][l-local 256 +8] (67.6 KB)
    __shared__ float Rbuf[4][2][64][16]; // kh-pair reduce (32 KB)

    const short* Qn  = Qf + (size_t)n * 524288;
    const short* Kn  = Kf + (size_t)n * 524288;
    const short* Vpn = Vs + (size_t)n * 524288;

    // resident Q B-frags (4 m-tiles x 4 slices = 64 VGPR)
    short8 qf[4][4];
    #pragma unroll
    for (int mst = 0; mst < 4; ++mst)
        #pragma unroll
        for (int s = 0; s < 4; ++s)
            qf[mst][s] = *(const short8*)(const void*)(
                Qn + (size_t)((m0 >> 4) + mst) * 2048 + s * 512 + lane * 8);

    floatx16 acc;
    #pragma unroll
    for (int r = 0; r < 16; ++r) acc[r] = 0.f;

    for (int step = 0; step < 16; ++step) {
        const int lb = step << 8;       // 256 l per step
        const int p  = step & 1;

        // ---- phase A: wave w -> S rows [lb+16w..+16) x 64 m -> P[p] ----
        short8 kfr[4];
        #pragma unroll
        for (int s = 0; s < 4; ++s)
            kfr[s] = *(const short8*)(const void*)(
                Kn + (size_t)(step * 16 + wave) * 2048 + s * 512 + lane * 8);

        #pragma unroll
        for (int mst = 0; mst < 4; ++mst) {
            floatx4 sa = {0.f, 0.f, 0.f, 0.f};
            #pragma unroll
            for (int s = 0; s < 4; ++s)
                sa = __builtin_amdgcn_mfma_f32_16x16x32_bf16(kfr[s], qf[mst][s], sa, 0, 0, 0);
            short4b pv;
            #pragma unroll
            for (int r = 0; r < 4; ++r) pv[r] = f2bf(__expf(sa[r]));
            // C-layout (row=l=4q+r, col=m=mc) -> P[m][l-local]
            *(short4b*)(void*)&P[p][16 * mst + mc][16 * wave + quad * 4] = pv;
        }
        __syncthreads();   // only barrier: P[p] visible

        // ---- phase B: V' panel x P[p]; wave covers kc-half (8 chunks) ----
        #pragma unroll
        for (int i = 0; i < 8; ++i) {
            const int kc = kh * 8 + i;  // 16-l chunk within the 256-l step
            const short8 vf = *(const short8*)(const void*)(
                Vpn + (size_t)((lb >> 4) + kc) * 2048 + (32 * ct + l32) * 16 + 8 * h);
            const short8 pf = *(const short8*)(const void*)&P[p][32 * mh + l32][16 * kc + 8 * h];
            acc = __builtin_amdgcn_mfma_f32_32x32x16_bf16(vf, pf, acc, 0, 0, 0);
        }
        // no trailing barrier: next step writes P[p^1]
    }

    // ---- kh-pair reduce + epilogue (32x32 C-layout) ----
    __syncthreads();
    if (kh == 1)
        *(floatx16*)(void*)&Rbuf[ct][mh][lane][0] = acc;
    __syncthreads();
    if (kh == 0) {
        const floatx16 o = *(const floatx16*)(const void*)&Rbuf[ct][mh][lane][0];
        #pragma unroll
        for (int r = 0; r < 16; ++r) {
            const int c = 32 * ct + (r & 3) + 8 * (r >> 2) + 4 * h;
            const int m = m0 + 32 * mh + l32;
            const size_t idx = ((size_t)n * CH + c) * LL + m;
            out[idx] = x[idx] + acc[r] + o[r];
        }
    }
}

// ---------------------------------------------------------------------------
extern "C" void kernel_launch(void* const* d_in, const int* in_sizes, int n_in,
                              void* d_out, int out_size, void* d_ws, size_t ws_size,
                              hipStream_t stream) {
    (void)in_sizes; (void)n_in; (void)out_size; (void)ws_size;
    const float* x  = (const float*)d_in[0];
    const float* Wq = (const float*)d_in[1];
    const float* bq = (const float*)d_in[2];
    const float* Wk = (const float*)d_in[3];
    const float* bk = (const float*)d_in[4];
    const float* Wv = (const float*)d_in[5];
    const float* bv = (const float*)d_in[6];
    float* out = (float*)d_out;

    char* ws = (char*)d_ws;
    // ws: Qf 4MB | Kf 4MB | Vp 4MB | Vs 4MB  (16 MB)
    short* Qf = (short*)(ws);
    short* Kf = (short*)(ws + 4194304);
    short* Vp = (short*)(ws + 8388608);
    short* Vs = (short*)(ws + 12582912);

    proj_kernel<<<512, 256, 0, stream>>>(x, Wq, bq, Wk, bk, Wv, bv, Qf, Kf, Vp);
    rowsum_kernel<<<512, 256, 0, stream>>>(Qf, Kf, Vp, Vs);
    attn_out_kernel<<<256, 1024, 0, stream>>>(Qf, Kf, Vs, x, out);
}

// Round 14
// 166.400 us; speedup vs baseline: 1.0950x; 1.0950x over previous
//
#include <hip/hip_runtime.h>
#include <hip/hip_bf16.h>
#include <stdint.h>

// Problem constants (N,C,H,W = 4,128,64,64)
#define NB 4
#define CH 128
#define LL 4096   // H*W

typedef __attribute__((ext_vector_type(8))) short short8;   // 8 bf16 MFMA A/B frag
typedef __attribute__((ext_vector_type(4))) short short4b;  // 4 bf16 (8B)
typedef __attribute__((ext_vector_type(4))) float floatx4;  // 16x16 C/D frag
typedef __attribute__((ext_vector_type(16))) float floatx16; // 32x32 C/D frag

// Frag-major layout (verified R9-R13): element (row r, k) of 16-wide tile t:
//   t*2048 + (k>>5)*512 + ((k>>3)&3)*128 + (r&15)*8 + (k&7)
// One 16x16x32 frag (tile t, slice s) = 512 contiguous shorts; lane L reads
// [8L, 8L+8) — fully coalesced; identical mapping for A- and B-frags.

static __device__ __forceinline__ short f2bf(float f) {
    uint32_t u = __float_as_uint(f);
    u += 0x7fffu + ((u >> 16) & 1u);
    return (short)(u >> 16);
}
static __device__ __forceinline__ float bf2f(short s) {
    return __uint_as_float(((uint32_t)(uint16_t)s) << 16);
}

// ---------------------------------------------------------------------------
// Kernel 0: W prep — Wq/Wk/Wv fp32 [o][c] -> bf16 frag-major A-layout
// (rows=o, k=c). K-scale folded into Wk. RESTORED (R13's inline W cvt made
// proj's W loads a 16-line scatter; this keeps them coalesced + L1-hot).
// ---------------------------------------------------------------------------
__global__ __launch_bounds__(256) void wprep_kernel(
    const float* __restrict__ Wq, const float* __restrict__ Wk,
    const float* __restrict__ Wv, short* __restrict__ Wf)
{
    const int g = blockIdx.x * 256 + threadIdx.x;   // 0..49151
    const int mat = g >> 14;
    const int rem = g & 16383;
    const int o   = rem >> 7;
    const int c   = rem & 127;
    const float* W = (mat == 0) ? Wq : (mat == 1) ? Wk : Wv;
    float v = W[o * CH + c];
    if (mat == 1) v *= 0.08838834764831845f;
    Wf[(size_t)mat * 16384 + (o >> 4) * 2048 + (c >> 5) * 512
       + ((c >> 3) & 3) * 128 + (o & 15) * 8 + (c & 7)] = f2bf(v);
}

// ---------------------------------------------------------------------------
// Kernel 1: QKV projection via MFMA (R12-proven structure). x read once;
// W A-frags coalesced from Wf (L1-hot 96 KB). Outputs Qf/Kf frag-major,
// Vp panel [n][l>>4][c][l&15]. grid = 4n*128 lt = 512 blocks x 256 thr.
// ---------------------------------------------------------------------------
__global__ __launch_bounds__(256) void proj_kernel(
    const float* __restrict__ x, const short* __restrict__ Wf,
    const float* __restrict__ bq, const float* __restrict__ bk,
    const float* __restrict__ bv,
    short* __restrict__ Qf, short* __restrict__ Kf, short* __restrict__ Vp)
{
    const int b    = blockIdx.x;
    const int n    = b >> 7;
    const int lt   = b & 127;         // l-tile of 32
    const int l0   = lt << 5;
    const int tid  = threadIdx.x;
    const int wave = tid >> 6;        // 0..3
    const int lane = tid & 63;
    const int quad = lane >> 4;
    const int mc   = lane & 15;

    __shared__ short Xb[32][136];     // [l][c] bf16, +8 pad (8.7 KB)

    {
        const int sl = tid & 31;      // l
        const int cg = tid >> 5;      // c-group of 16 (0..7)
        const float* xp = x + ((size_t)n * CH + cg * 16) * LL + l0 + sl;
        short8 buf;
        #pragma unroll
        for (int i = 0; i < 16; ++i) {
            buf[i & 7] = f2bf(xp[(size_t)i * LL]);
            if ((i & 7) == 7)
                *(short8*)(void*)&Xb[sl][cg * 16 + (i & 8)] = buf;
        }
    }
    __syncthreads();

    const int lt2 = wave >> 1;        // l-subtile of 16
    const int oh  = wave & 1;         // o-half (4 o-tiles)
    const int gt  = lt * 2 + lt2;     // global 16-l tile index

    short8 xf[4];                     // B-frags: B[k=c][col=l]
    #pragma unroll
    for (int s = 0; s < 4; ++s)
        xf[s] = *(const short8*)(const void*)&Xb[lt2 * 16 + mc][32 * s + quad * 8];

    const size_t obase = ((size_t)n * 256 + gt) * 2048;
    const float scale = 0.08838834764831845f;  // 1/sqrt(128)

    #pragma unroll
    for (int mat = 0; mat < 3; ++mat) {
        const short* Wm = Wf + (size_t)mat * 16384;
        const float* bb = (mat == 0) ? bq : (mat == 1) ? bk : bv;
        const float bscale = (mat == 1) ? scale : 1.0f;
        #pragma unroll
        for (int ot = oh * 4; ot < oh * 4 + 4; ++ot) {
            floatx4 acc = {0.f, 0.f, 0.f, 0.f};
            #pragma unroll
            for (int s = 0; s < 4; ++s)
                acc = __builtin_amdgcn_mfma_f32_16x16x32_bf16(
                    *(const short8*)(const void*)(Wm + ot * 2048 + s * 512 + lane * 8),
                    xf[s], acc, 0, 0, 0);
            const int c0 = ot * 16 + 4 * quad;
            if (mat < 2) {
                short4b pv;
                #pragma unroll
                for (int r = 0; r < 4; ++r)
                    pv[r] = f2bf(acc[r] + bb[c0 + r] * bscale);
                short* dst = ((mat == 0) ? Qf : Kf) + obase
                           + (c0 >> 5) * 512 + ((c0 >> 3) & 3) * 128
                           + mc * 8 + (c0 & 7);
                *(short4b*)(void*)dst = pv;
            } else {
                #pragma unroll
                for (int r = 0; r < 4; ++r)
                    Vp[obase + (c0 + r) * 16 + mc] = f2bf(acc[r] + bb[c0 + r]);
            }
        }
    }
}

// ---------------------------------------------------------------------------
// Kernel 2: softmax denominators + V scaling, fused (unchanged from R13).
// Block owns 32 l: 2 K-tiles/wave resident, LDS combine (no atomics, no
// memset), then writes Vs[:, l-slice] = Vp * (1/D[l]).
// grid = 4n * 128 tp = 512 blocks x 256 thr.
// ---------------------------------------------------------------------------
__global__ __launch_bounds__(256) void rowsum_kernel(
    const short* __restrict__ Qf, const short* __restrict__ Kf,
    const short* __restrict__ Vp, short* __restrict__ Vs)
{
    const int b    = blockIdx.x;
    const int n    = b >> 7;
    const int tp   = b & 127;            // K-tile pair (32 l)
    const int tid  = threadIdx.x;
    const int wave = tid >> 6;           // m-quarter
    const int lane = tid & 63;
    const int quad = lane >> 4;
    const int mc   = lane & 15;

    __shared__ float Db[4][32];          // per-wave partial D
    __shared__ float Dr[32];             // rcpD for local 32 l

    const short* Kb = Kf + ((size_t)n * 256 + tp * 2) * 2048 + lane * 8;
    short8 kf[2][4];
    #pragma unroll
    for (int t = 0; t < 2; ++t)
        #pragma unroll
        for (int s = 0; s < 4; ++s)
            kf[t][s] = *(const short8*)(const void*)(Kb + t * 2048 + s * 512);

    const short* Qn = Qf + (size_t)n * 524288 + (size_t)wave * 64 * 2048 + lane * 8;
    float rs[2][4] = {{0.f,0.f,0.f,0.f},{0.f,0.f,0.f,0.f}};

    for (int i = 0; i < 64; i += 2) {        // 4 independent MFMA chains
        floatx4 a[2][2];
        #pragma unroll
        for (int t = 0; t < 2; ++t)
            #pragma unroll
            for (int j = 0; j < 2; ++j) a[t][j] = (floatx4){0.f,0.f,0.f,0.f};
        #pragma unroll
        for (int s = 0; s < 4; ++s) {
            const short8 q0 = *(const short8*)(const void*)(Qn + (size_t)i * 2048 + s * 512);
            const short8 q1 = *(const short8*)(const void*)(Qn + (size_t)(i + 1) * 2048 + s * 512);
            #pragma unroll
            for (int t = 0; t < 2; ++t) {
                a[t][0] = __builtin_amdgcn_mfma_f32_16x16x32_bf16(kf[t][s], q0, a[t][0], 0, 0, 0);
                a[t][1] = __builtin_amdgcn_mfma_f32_16x16x32_bf16(kf[t][s], q1, a[t][1], 0, 0, 0);
            }
        }
        #pragma unroll
        for (int t = 0; t < 2; ++t)
            #pragma unroll
            for (int j = 0; j < 2; ++j)
                #pragma unroll
                for (int r = 0; r < 4; ++r) rs[t][r] += __expf(a[t][j][r]);
    }

    #pragma unroll
    for (int t = 0; t < 2; ++t) {
        #pragma unroll
        for (int r = 0; r < 4; ++r) {        // reduce over m (col lanes)
            float v = rs[t][r];
            v += __shfl_xor(v, 1);
            v += __shfl_xor(v, 2);
            v += __shfl_xor(v, 4);
            v += __shfl_xor(v, 8);
            rs[t][r] = v;
        }
        if (mc == 0) {
            #pragma unroll
            for (int r = 0; r < 4; ++r)      // local l = t*16 + quad*4 + r
                Db[wave][t * 16 + quad * 4 + r] = rs[t][r];
        }
    }
    __syncthreads();
    if (tid < 32)
        Dr[tid] = 1.0f / (Db[0][tid] + Db[1][tid] + Db[2][tid] + Db[3][tid]);
    __syncthreads();

    // ---- fused V scaling: Vs[:, l-slice] = Vp * rcpD[l] ----
    const short* vsrc = Vp + ((size_t)n * 256 + tp * 2) * 2048;
    short*       vdst = Vs + ((size_t)n * 256 + tp * 2) * 2048;
    #pragma unroll
    for (int k = 0; k < 16; ++k) {
        const int i = k * 256 + tid;         // 0..4095, coalesced
        const int tile = i >> 11;            // 0/1
        const int li   = i & 15;
        vdst[i] = f2bf(bf2f(vsrc[i]) * Dr[tile * 16 + li]);
    }
}

// ---------------------------------------------------------------------------
// Kernel 3: O[c,m] = sum_l V'[c,l]*exp(S[l,m]);  out = x + O  (unchanged
// from R13: m-block 64, 1024 thr, Q resident, P dbuf, 1 barrier/step).
// grid = 4n * 64 m-blocks = 256 blocks x 1024 thr.
// ---------------------------------------------------------------------------
__global__ __launch_bounds__(1024) void attn_out_kernel(
    const short* __restrict__ Qf, const short* __restrict__ Kf,
    const short* __restrict__ Vs,
    const float* __restrict__ x, float* __restrict__ out)
{
    const int b    = blockIdx.x;
    const int n    = b >> 6;
    const int m0   = (b & 63) << 6;     // m-block of 64
    const int tid  = threadIdx.x;
    const int wave = tid >> 6;          // 0..15
    const int lane = tid & 63;
    const int quad = lane >> 4;
    const int mc   = lane & 15;
    const int l32  = lane & 31;
    const int h    = lane >> 5;
    const int ct   = wave & 3;          // c-tile (32 channels)
    const int mh   = (wave >> 2) & 1;   // m-half (32 cols)
    const int kh   = wave >> 3;         // kc-half

    __shared__ short P[2][64][264];     // dbuf [m][l-local 256 +8] (67.6 KB)
    __shared__ float Rbuf[4][2][64][16]; // kh-pair reduce (32 KB)

    const short* Qn  = Qf + (size_t)n * 524288;
    const short* Kn  = Kf + (size_t)n * 524288;
    const short* Vpn = Vs + (size_t)n * 524288;

    // resident Q B-frags (4 m-tiles x 4 slices = 64 VGPR)
    short8 qf[4][4];
    #pragma unroll
    for (int mst = 0; mst < 4; ++mst)
        #pragma unroll
        for (int s = 0; s < 4; ++s)
            qf[mst][s] = *(const short8*)(const void*)(
                Qn + (size_t)((m0 >> 4) + mst) * 2048 + s * 512 + lane * 8);

    floatx16 acc;
    #pragma unroll
    for (int r = 0; r < 16; ++r) acc[r] = 0.f;

    for (int step = 0; step < 16; ++step) {
        const int lb = step << 8;       // 256 l per step
        const int p  = step & 1;

        // ---- phase A: wave w -> S rows [lb+16w..+16) x 64 m -> P[p] ----
        short8 kfr[4];
        #pragma unroll
        for (int s = 0; s < 4; ++s)
            kfr[s] = *(const short8*)(const void*)(
                Kn + (size_t)(step * 16 + wave) * 2048 + s * 512 + lane * 8);

        #pragma unroll
        for (int mst = 0; mst < 4; ++mst) {
            floatx4 sa = {0.f, 0.f, 0.f, 0.f};
            #pragma unroll
            for (int s = 0; s < 4; ++s)
                sa = __builtin_amdgcn_mfma_f32_16x16x32_bf16(kfr[s], qf[mst][s], sa, 0, 0, 0);
            short4b pv;
            #pragma unroll
            for (int r = 0; r < 4; ++r) pv[r] = f2bf(__expf(sa[r]));
            // C-layout (row=l=4q+r, col=m=mc) -> P[m][l-local]
            *(short4b*)(void*)&P[p][16 * mst + mc][16 * wave + quad * 4] = pv;
        }
        __syncthreads();   // only barrier: P[p] visible

        // ---- phase B: V' panel x P[p]; wave covers kc-half (8 chunks) ----
        #pragma unroll
        for (int i = 0; i < 8; ++i) {
            const int kc = kh * 8 + i;  // 16-l chunk within the 256-l step
            const short8 vf = *(const short8*)(const void*)(
                Vpn + (size_t)((lb >> 4) + kc) * 2048 + (32 * ct + l32) * 16 + 8 * h);
            const short8 pf = *(const short8*)(const void*)&P[p][32 * mh + l32][16 * kc + 8 * h];
            acc = __builtin_amdgcn_mfma_f32_32x32x16_bf16(vf, pf, acc, 0, 0, 0);
        }
        // no trailing barrier: next step writes P[p^1]
    }

    // ---- kh-pair reduce + epilogue (32x32 C-layout) ----
    __syncthreads();
    if (kh == 1)
        *(floatx16*)(void*)&Rbuf[ct][mh][lane][0] = acc;
    __syncthreads();
    if (kh == 0) {
        const floatx16 o = *(const floatx16*)(const void*)&Rbuf[ct][mh][lane][0];
        #pragma unroll
        for (int r = 0; r < 16; ++r) {
            const int c = 32 * ct + (r & 3) + 8 * (r >> 2) + 4 * h;
            const int m = m0 + 32 * mh + l32;
            const size_t idx = ((size_t)n * CH + c) * LL + m;
            out[idx] = x[idx] + acc[r] + o[r];
        }
    }
}

// ---------------------------------------------------------------------------
extern "C" void kernel_launch(void* const* d_in, const int* in_sizes, int n_in,
                              void* d_out, int out_size, void* d_ws, size_t ws_size,
                              hipStream_t stream) {
    (void)in_sizes; (void)n_in; (void)out_size; (void)ws_size;
    const float* x  = (const float*)d_in[0];
    const float* Wq = (const float*)d_in[1];
    const float* bq = (const float*)d_in[2];
    const float* Wk = (const float*)d_in[3];
    const float* bk = (const float*)d_in[4];
    const float* Wv = (const float*)d_in[5];
    const float* bv = (const float*)d_in[6];
    float* out = (float*)d_out;

    char* ws = (char*)d_ws;
    // ws: Qf 4MB | Kf 4MB | Vp 4MB | Vs 4MB | Wf 96KB  (~16.9 MB)
    short* Qf = (short*)(ws);
    short* Kf = (short*)(ws + 4194304);
    short* Vp = (short*)(ws + 8388608);
    short* Vs = (short*)(ws + 12582912);
    short* Wf = (short*)(ws + 16777216);

    wprep_kernel<<<192, 256, 0, stream>>>(Wq, Wk, Wv, Wf);
    proj_kernel<<<512, 256, 0, stream>>>(x, Wf, bq, bk, bv, Qf, Kf, Vp);
    rowsum_kernel<<<512, 256, 0, stream>>>(Qf, Kf, Vp, Vs);
    attn_out_kernel<<<256, 1024, 0, stream>>>(Qf, Kf, Vs, x, out);
}